// Round 1
// baseline (1690.288 us; speedup 1.0000x reference)
//
#include <hip/hip_runtime.h>
#include <math.h>

#define S_LEN 4096
#define BATCH 8
#define DDIM  2048
#define CDIM  64
#define HDIM  16

// ws layout: xg (padded to 4104 steps) then comp
#define XG_F4_COUNT ((size_t)(S_LEN + 8) * BATCH * HDIM)     // float4 count
#define COMP_OFF_BYTES (XG_F4_COUNT * sizeof(float4))         // 8,404,992 B

__device__ __forceinline__ float gelu_exact(float x) {
  return 0.5f * x * (1.0f + erff(x * 0.70710678118654752f));
}

// ---------------- K1: compressed = gelu(residual @ Wc^T + cb) ----------------
// A: [32768][2048], W: [64][2048], comp: [32768][64]
// block 256 thr, tile M=128 x C=64, KT=32. ty=tid>>3 (rows 4ty..), tx=tid&7 (cols 8tx..)
__global__ __launch_bounds__(256) void k1_compress(
    const float* __restrict__ A, const float* __restrict__ W,
    const float* __restrict__ cb, float* __restrict__ comp) {
  __shared__ float As[32][132];   // [k][row], stride 132 floats = 528B (16B aligned)
  __shared__ float Ws[32][72];    // [k][col], stride 288B (16B aligned)
  const int tid = threadIdx.x;
  const int m0 = blockIdx.x * 128;
  const int ty = tid >> 3;
  const int tx = tid & 7;

  float acc[4][8];
  #pragma unroll
  for (int r = 0; r < 4; r++)
    #pragma unroll
    for (int c = 0; c < 8; c++) acc[r][c] = 0.f;

  for (int kt = 0; kt < DDIM; kt += 32) {
    // stage A tile (128 rows x 32 k), transposed into As[k][row]
    #pragma unroll
    for (int p = 0; p < 4; p++) {
      const int r = p * 32 + (tid >> 3);
      const int k = (tid & 7) << 2;
      const float4 v = *(const float4*)&A[(size_t)(m0 + r) * DDIM + kt + k];
      As[k + 0][r] = v.x; As[k + 1][r] = v.y; As[k + 2][r] = v.z; As[k + 3][r] = v.w;
    }
    // stage W tile (64 cols x 32 k), transposed into Ws[k][col]
    #pragma unroll
    for (int e = 0; e < 2; e++) {
      const int slot = tid * 2 + e;        // 0..511
      const int c = slot >> 3;
      const int k = (slot & 7) << 2;
      const float4 v = *(const float4*)&W[(size_t)c * DDIM + kt + k];
      Ws[k + 0][c] = v.x; Ws[k + 1][c] = v.y; Ws[k + 2][c] = v.z; Ws[k + 3][c] = v.w;
    }
    __syncthreads();
    #pragma unroll
    for (int k = 0; k < 32; k++) {
      const float4 a  = *(const float4*)&As[k][ty << 2];
      const float4 w0 = *(const float4*)&Ws[k][tx << 3];
      const float4 w1 = *(const float4*)&Ws[k][(tx << 3) + 4];
      const float av[4] = {a.x, a.y, a.z, a.w};
      const float wv[8] = {w0.x, w0.y, w0.z, w0.w, w1.x, w1.y, w1.z, w1.w};
      #pragma unroll
      for (int r = 0; r < 4; r++)
        #pragma unroll
        for (int c = 0; c < 8; c++) acc[r][c] += av[r] * wv[c];
    }
    __syncthreads();
  }

  float cbv[8];
  #pragma unroll
  for (int e = 0; e < 8; e++) cbv[e] = cb[(tx << 3) + e];
  #pragma unroll
  for (int rr = 0; rr < 4; rr++) {
    const int m = m0 + (ty << 2) + rr;
    float o[8];
    #pragma unroll
    for (int c = 0; c < 8; c++) o[c] = gelu_exact(acc[rr][c] + cbv[c]);
    float4* dst = (float4*)(comp + (size_t)m * CDIM + (tx << 3));
    dst[0] = make_float4(o[0], o[1], o[2], o[3]);
    dst[1] = make_float4(o[4], o[5], o[6], o[7]);
  }
}

// ---------------- K2: x_gates = comp @ w_ih^T + b_ih (+ fold b_hr, b_hz) ----
// one lane = one row m. w_ih reads are wave-uniform -> scalar loads.
// output layout: xg[(s*8+b)*16 + i] = float4(xr+bhr, xz+bhz, xn, 0)
__global__ __launch_bounds__(64) void k2_gates(
    const float* __restrict__ comp, const float* __restrict__ w_ih,
    const float* __restrict__ b_ih, const float* __restrict__ b_hh,
    float4* __restrict__ xg) {
  const int m = (blockIdx.x << 6) + threadIdx.x;
  const int b = m >> 12;
  const int s = m & 4095;
  float c[64];
  const float4* cp = (const float4*)(comp + (size_t)m * CDIM);
  #pragma unroll
  for (int e = 0; e < 16; e++) {
    const float4 v = cp[e];
    c[e * 4 + 0] = v.x; c[e * 4 + 1] = v.y; c[e * 4 + 2] = v.z; c[e * 4 + 3] = v.w;
  }
  float4* xo = xg + ((size_t)((s << 3) + b) << 4);
  #pragma unroll
  for (int i = 0; i < 16; i++) {
    float a0 = b_ih[i]      + b_hh[i];
    float a1 = b_ih[16 + i] + b_hh[16 + i];
    float a2 = b_ih[32 + i];
    #pragma unroll
    for (int cc = 0; cc < 64; cc++) {
      const float cv = c[cc];
      a0 += cv * w_ih[((i)      << 6) + cc];
      a1 += cv * w_ih[((16 + i) << 6) + cc];
      a2 += cv * w_ih[((32 + i) << 6) + cc];
    }
    xo[i] = make_float4(a0, a1, a2, 0.f);
  }
}

// ---------------- K3: GRU scan ----------------
// 2 blocks x 64 threads; wave handles 4 batches (16 lanes each).
// lane (q,i): q=lane>>4 -> batch, i=lane&15 -> hidden unit.
// XOR-butterfly matvec: w*[k] = W[i][i^k]; hv_k = shfl_xor(h, k).
__global__ __launch_bounds__(64) void k3_gru(
    const float4* __restrict__ xg, const float* __restrict__ w_hh,
    const float* __restrict__ b_hh, float* __restrict__ out) {
  const int lane = threadIdx.x;
  const int q = lane >> 4;
  const int i = lane & 15;
  const int b = (blockIdx.x << 2) + q;

  float wr[16], wz[16], wn[16];
  #pragma unroll
  for (int k = 0; k < 16; k++) {
    const int j = i ^ k;
    wr[k] = w_hh[(i << 4) + j];
    wz[k] = w_hh[((16 + i) << 4) + j];
    wn[k] = w_hh[((32 + i) << 4) + j];
  }
  const float bhn = b_hh[32 + i];

  const float4* xp = xg + ((size_t)b << 4) + i;       // + t*128
  float* op = out + ((size_t)b << 16) + i;            // b*4096*16 + t*16 + i
  float h = 0.f;

  auto step = [&](const float4 f, const int t) {
    float ar = f.x, az = f.y, an = bhn;
    ar += h * wr[0]; az += h * wz[0]; an += h * wn[0];
    #pragma unroll
    for (int k = 1; k < 16; k++) {
      const float hv = __shfl_xor(h, k);
      ar += hv * wr[k]; az += hv * wz[k]; an += hv * wn[k];
    }
    const float r = __builtin_amdgcn_rcpf(1.f + __expf(-ar));
    const float z = __builtin_amdgcn_rcpf(1.f + __expf(-az));
    const float e2 = __expf(2.f * (f.z + r * an));
    const float n = 1.f - 2.f * __builtin_amdgcn_rcpf(1.f + e2);
    h = n + z * (h - n);
    op[(size_t)t << 4] = h;
  };

  float4 f0 = xp[0 * 128];
  float4 f1 = xp[1 * 128];
  float4 f2 = xp[2 * 128];
  float4 f3 = xp[3 * 128];
  for (int t = 0; t < S_LEN; t += 4) {
    // prefetch next group (reads into the 8-step pad on the last iter)
    const float4 n0 = xp[(size_t)(t + 4) * 128];
    const float4 n1 = xp[(size_t)(t + 5) * 128];
    const float4 n2 = xp[(size_t)(t + 6) * 128];
    const float4 n3 = xp[(size_t)(t + 7) * 128];
    step(f0, t); step(f1, t + 1); step(f2, t + 2); step(f3, t + 3);
    f0 = n0; f1 = n1; f2 = n2; f3 = n3;
  }
}

extern "C" void kernel_launch(void* const* d_in, const int* in_sizes, int n_in,
                              void* d_out, int out_size, void* d_ws, size_t ws_size,
                              hipStream_t stream) {
  (void)in_sizes; (void)n_in; (void)out_size; (void)ws_size;
  const float* residual   = (const float*)d_in[0];
  const float* compress_w = (const float*)d_in[1];
  const float* compress_b = (const float*)d_in[2];
  const float* w_ih       = (const float*)d_in[3];
  const float* w_hh       = (const float*)d_in[4];
  const float* b_ih       = (const float*)d_in[5];
  const float* b_hh       = (const float*)d_in[6];
  float* out = (float*)d_out;

  char* ws = (char*)d_ws;
  float4* xg = (float4*)ws;
  float* comp = (float*)(ws + COMP_OFF_BYTES);

  hipLaunchKernelGGL(k1_compress, dim3((BATCH * S_LEN) / 128), dim3(256), 0, stream,
                     residual, compress_w, compress_b, comp);
  hipLaunchKernelGGL(k2_gates, dim3((BATCH * S_LEN) / 64), dim3(64), 0, stream,
                     comp, w_ih, b_ih, b_hh, xg);
  hipLaunchKernelGGL(k3_gru, dim3(2), dim3(64), 0, stream,
                     xg, w_hh, b_hh, out);
}

// Round 2
// 1323.271 us; speedup vs baseline: 1.2774x; 1.2774x over previous
//
#include <hip/hip_runtime.h>
#include <math.h>

#define S_LEN 4096
#define BATCH 8
#define DDIM  2048
#define CDIM  64
#define HDIM  16

// ws layout: xg (padded to 4104 steps) then comp
#define XG_F4_COUNT ((size_t)(S_LEN + 8) * BATCH * HDIM)     // float4 count
#define COMP_OFF_BYTES (XG_F4_COUNT * sizeof(float4))         // 8,404,992 B

__device__ __forceinline__ float gelu_exact(float x) {
  return 0.5f * x * (1.0f + erff(x * 0.70710678118654752f));
}

// ---------------- K1: compressed = gelu(residual @ Wc^T + cb) ----------------
// A: [32768][2048], W: [64][2048], comp: [32768][64]
// block 256 thr, tile M=128 x C=64, KT=32. ty=tid>>3 (rows 4ty..), tx=tid&7 (cols 8tx..)
__global__ __launch_bounds__(256) void k1_compress(
    const float* __restrict__ A, const float* __restrict__ W,
    const float* __restrict__ cb, float* __restrict__ comp) {
  __shared__ float As[32][132];   // [k][row], stride 132 floats = 528B (16B aligned)
  __shared__ float Ws[32][72];    // [k][col], stride 288B (16B aligned)
  const int tid = threadIdx.x;
  const int m0 = blockIdx.x * 128;
  const int ty = tid >> 3;
  const int tx = tid & 7;

  float acc[4][8];
  #pragma unroll
  for (int r = 0; r < 4; r++)
    #pragma unroll
    for (int c = 0; c < 8; c++) acc[r][c] = 0.f;

  for (int kt = 0; kt < DDIM; kt += 32) {
    // stage A tile (128 rows x 32 k), transposed into As[k][row]
    #pragma unroll
    for (int p = 0; p < 4; p++) {
      const int r = p * 32 + (tid >> 3);
      const int k = (tid & 7) << 2;
      const float4 v = *(const float4*)&A[(size_t)(m0 + r) * DDIM + kt + k];
      As[k + 0][r] = v.x; As[k + 1][r] = v.y; As[k + 2][r] = v.z; As[k + 3][r] = v.w;
    }
    // stage W tile (64 cols x 32 k), transposed into Ws[k][col]
    #pragma unroll
    for (int e = 0; e < 2; e++) {
      const int slot = tid * 2 + e;        // 0..511
      const int c = slot >> 3;
      const int k = (slot & 7) << 2;
      const float4 v = *(const float4*)&W[(size_t)c * DDIM + kt + k];
      Ws[k + 0][c] = v.x; Ws[k + 1][c] = v.y; Ws[k + 2][c] = v.z; Ws[k + 3][c] = v.w;
    }
    __syncthreads();
    #pragma unroll
    for (int k = 0; k < 32; k++) {
      const float4 a  = *(const float4*)&As[k][ty << 2];
      const float4 w0 = *(const float4*)&Ws[k][tx << 3];
      const float4 w1 = *(const float4*)&Ws[k][(tx << 3) + 4];
      const float av[4] = {a.x, a.y, a.z, a.w};
      const float wv[8] = {w0.x, w0.y, w0.z, w0.w, w1.x, w1.y, w1.z, w1.w};
      #pragma unroll
      for (int r = 0; r < 4; r++)
        #pragma unroll
        for (int c = 0; c < 8; c++) acc[r][c] += av[r] * wv[c];
    }
    __syncthreads();
  }

  float cbv[8];
  #pragma unroll
  for (int e = 0; e < 8; e++) cbv[e] = cb[(tx << 3) + e];
  #pragma unroll
  for (int rr = 0; rr < 4; rr++) {
    const int m = m0 + (ty << 2) + rr;
    float o[8];
    #pragma unroll
    for (int c = 0; c < 8; c++) o[c] = gelu_exact(acc[rr][c] + cbv[c]);
    float4* dst = (float4*)(comp + (size_t)m * CDIM + (tx << 3));
    dst[0] = make_float4(o[0], o[1], o[2], o[3]);
    dst[1] = make_float4(o[4], o[5], o[6], o[7]);
  }
}

// ---------------- K2: x_gates = comp @ w_ih^T + b_ih (+ fold b_hr, b_hz) ----
// one lane = one row m. w_ih reads are wave-uniform -> scalar loads.
// output layout: xg[(s*8+b)*16 + i] = float4(xr+bhr, xz+bhz, xn, 0)
__global__ __launch_bounds__(64) void k2_gates(
    const float* __restrict__ comp, const float* __restrict__ w_ih,
    const float* __restrict__ b_ih, const float* __restrict__ b_hh,
    float4* __restrict__ xg) {
  const int m = (blockIdx.x << 6) + threadIdx.x;
  const int b = m >> 12;
  const int s = m & 4095;
  float c[64];
  const float4* cp = (const float4*)(comp + (size_t)m * CDIM);
  #pragma unroll
  for (int e = 0; e < 16; e++) {
    const float4 v = cp[e];
    c[e * 4 + 0] = v.x; c[e * 4 + 1] = v.y; c[e * 4 + 2] = v.z; c[e * 4 + 3] = v.w;
  }
  float4* xo = xg + ((size_t)((s << 3) + b) << 4);
  #pragma unroll
  for (int i = 0; i < 16; i++) {
    float a0 = b_ih[i]      + b_hh[i];
    float a1 = b_ih[16 + i] + b_hh[16 + i];
    float a2 = b_ih[32 + i];
    #pragma unroll
    for (int cc = 0; cc < 64; cc++) {
      const float cv = c[cc];
      a0 += cv * w_ih[((i)      << 6) + cc];
      a1 += cv * w_ih[((16 + i) << 6) + cc];
      a2 += cv * w_ih[((32 + i) << 6) + cc];
    }
    xo[i] = make_float4(a0, a1, a2, 0.f);
  }
}

// ---------------- K3: GRU scan ----------------
// 2 blocks x 64 threads; wave handles 4 batches (16 lanes each).
// lane (q,i): q=lane>>4 -> batch, i=lane&15 -> hidden unit.
// Rotation matvec via DPP row_ror (VALU pipe, ~3cyc dep latency) instead of
// __shfl_xor (ds_swizzle, ~120cyc LDS latency). The permutation direction is
// probed at runtime on a lane-id value, so weight gather matches whatever the
// HW semantics of row_ror:K are — zero directional risk.
__global__ __launch_bounds__(64) void k3_gru(
    const float4* __restrict__ xg, const float* __restrict__ w_hh,
    const float* __restrict__ b_hh, float* __restrict__ out) {
  const int lane = threadIdx.x;
  const int q = lane >> 4;
  const int i = lane & 15;
  const int b = (blockIdx.x << 2) + q;

  float wr[16], wz[16], wn[16];
  // k=0: own lane (diagonal)
  wr[0] = w_hh[(i << 4) + i];
  wz[0] = w_hh[((16 + i) << 4) + i];
  wn[0] = w_hh[((32 + i) << 4) + i];
  // probe the actual row_ror:K source lane, gather matching weight column
#define PROBE(K) { \
    const int s_ = __builtin_amdgcn_update_dpp(0, lane, 0x120 | K, 0xF, 0xF, true) & 15; \
    wr[K] = w_hh[(i << 4) + s_]; \
    wz[K] = w_hh[((16 + i) << 4) + s_]; \
    wn[K] = w_hh[((32 + i) << 4) + s_]; }
  PROBE(1) PROBE(2) PROBE(3) PROBE(4) PROBE(5) PROBE(6) PROBE(7) PROBE(8)
  PROBE(9) PROBE(10) PROBE(11) PROBE(12) PROBE(13) PROBE(14) PROBE(15)
#undef PROBE
  const float bhn = b_hh[32 + i];

  const float4* xp = xg + ((size_t)b << 4) + i;       // + t*128
  float* op = out + ((size_t)b << 16) + i;            // b*4096*16 + t*16 + i
  float h = 0.f;

  auto step = [&](const float4 f, const int t) {
    float ar = f.x + h * wr[0];
    float az = f.y + h * wz[0];
    float an = bhn + h * wn[0];
#define ACC(K) { \
    const float hv = __int_as_float( \
        __builtin_amdgcn_update_dpp(0, __float_as_int(h), 0x120 | K, 0xF, 0xF, true)); \
    ar += hv * wr[K]; az += hv * wz[K]; an += hv * wn[K]; }
    ACC(1) ACC(2) ACC(3) ACC(4) ACC(5) ACC(6) ACC(7) ACC(8)
    ACC(9) ACC(10) ACC(11) ACC(12) ACC(13) ACC(14) ACC(15)
#undef ACC
    const float r = __builtin_amdgcn_rcpf(1.f + __expf(-ar));
    const float z = __builtin_amdgcn_rcpf(1.f + __expf(-az));
    const float e2 = __expf(2.f * (f.z + r * an));
    const float n = 1.f - 2.f * __builtin_amdgcn_rcpf(1.f + e2);
    h = n + z * (h - n);
    op[(size_t)t << 4] = h;
  };

  float4 f0 = xp[0 * 128];
  float4 f1 = xp[1 * 128];
  float4 f2 = xp[2 * 128];
  float4 f3 = xp[3 * 128];
  for (int t = 0; t < S_LEN; t += 4) {
    // prefetch next group (reads into the 8-step pad on the last iter)
    const float4 n0 = xp[(size_t)(t + 4) * 128];
    const float4 n1 = xp[(size_t)(t + 5) * 128];
    const float4 n2 = xp[(size_t)(t + 6) * 128];
    const float4 n3 = xp[(size_t)(t + 7) * 128];
    step(f0, t); step(f1, t + 1); step(f2, t + 2); step(f3, t + 3);
    f0 = n0; f1 = n1; f2 = n2; f3 = n3;
  }
}

extern "C" void kernel_launch(void* const* d_in, const int* in_sizes, int n_in,
                              void* d_out, int out_size, void* d_ws, size_t ws_size,
                              hipStream_t stream) {
  (void)in_sizes; (void)n_in; (void)out_size; (void)ws_size;
  const float* residual   = (const float*)d_in[0];
  const float* compress_w = (const float*)d_in[1];
  const float* compress_b = (const float*)d_in[2];
  const float* w_ih       = (const float*)d_in[3];
  const float* w_hh       = (const float*)d_in[4];
  const float* b_ih       = (const float*)d_in[5];
  const float* b_hh       = (const float*)d_in[6];
  float* out = (float*)d_out;

  char* ws = (char*)d_ws;
  float4* xg = (float4*)ws;
  float* comp = (float*)(ws + COMP_OFF_BYTES);

  hipLaunchKernelGGL(k1_compress, dim3((BATCH * S_LEN) / 128), dim3(256), 0, stream,
                     residual, compress_w, compress_b, comp);
  hipLaunchKernelGGL(k2_gates, dim3((BATCH * S_LEN) / 64), dim3(64), 0, stream,
                     comp, w_ih, b_ih, b_hh, xg);
  hipLaunchKernelGGL(k3_gru, dim3(2), dim3(64), 0, stream,
                     xg, w_hh, b_hh, out);
}